// Round 4
// 305.586 us; speedup vs baseline: 1.0003x; 1.0003x over previous
//
#include <hip/hip_runtime.h>
#include <stdint.h>
#include <math.h>

// CONTROL EXPERIMENT: exact round-0 kernel (previously PASSED, 304.4 us).
// Rounds 1-3 (v2) failed with bit-identical absmax 7.683964931e9 including one
// clean-push run. This submission bisects: same-failure => corrupted cached
// data / infra (no kernel can pass); pass => v2 carries a real bug, bisect it.

#define EPS 1e-5f
constexpr int B = 8, C = 128, Ci = 32, H = 128, W = 256;
constexpr int HW = H * W;      // 32768 = 2^15
constexpr int P  = B * HW;     // 262144 pixels total

// ws layout (uint32 units):
// [0,128)    w1p   : per ci (32), 4 words over 128 input channels
// [128,416)  w2p   : per (ci,tap) 32 ci x 9 taps, 1 word over 32 input channels
// [416,544)  w3p   : per c (128), 1 word over 32 input channels
// [544,576)  T1    : float thresholds (32)
// [576,608)  T2    : float thresholds (32)
// [608,736)  inv3  : float (128)
// [736,864)  c3    : float (128)
// [1024, 1024+P)       s1
// [1024+P, 1024+2P)    s2
constexpr int WS_S1 = 1024;
constexpr int WS_S2 = 1024 + P;

__global__ __launch_bounds__(256) void prep_kernel(
    const float* __restrict__ w1,
    const float* __restrict__ g1, const float* __restrict__ b1,
    const float* __restrict__ m1, const float* __restrict__ v1,
    const float* __restrict__ w2,
    const float* __restrict__ g2, const float* __restrict__ b2,
    const float* __restrict__ m2, const float* __restrict__ v2,
    const float* __restrict__ w3,
    const float* __restrict__ g3, const float* __restrict__ b3,
    const float* __restrict__ m3, const float* __restrict__ v3,
    uint32_t* __restrict__ ws)
{
    int t = threadIdx.x;
    float* wsf = (float*)ws;

    if (t < 128) {  // w1 pack: ci = t>>2, word = t&3
        int ci = t >> 2, wd = t & 3;
        const float* src = w1 + ci * C + wd * 32;
        uint32_t m = 0;
        #pragma unroll
        for (int j = 0; j < 32; ++j) m |= (src[j] > 0.f ? 1u : 0u) << j;
        ws[t] = m;
    }
    for (int idx = t; idx < 288; idx += 256) {  // w2 pack: ci = idx/9, tap = idx%9
        int ci = idx / 9, tap = idx % 9;
        uint32_t m = 0;
        for (int cj = 0; cj < 32; ++cj)
            m |= (w2[(ci * Ci + cj) * 9 + tap] > 0.f ? 1u : 0u) << cj;
        ws[128 + idx] = m;
    }
    if (t < 128) {  // w3 pack
        const float* src = w3 + t * Ci;
        uint32_t m = 0;
        #pragma unroll
        for (int j = 0; j < 32; ++j) m |= (src[j] > 0.f ? 1u : 0u) << j;
        ws[416 + t] = m;
    }
    if (t < 32) {   // thresholds: T = m - b*sqrt(v+EPS)/g  (h<=0 <=> y<=T)
        float inv1 = g1[t] / sqrtf(v1[t] + EPS);
        wsf[544 + t] = m1[t] - b1[t] / inv1;
        float inv2 = g2[t] / sqrtf(v2[t] + EPS);
        wsf[576 + t] = m2[t] - b2[t] / inv2;
    }
    if (t < 128) {  // bn3 constants
        float i3 = g3[t] / sqrtf(v3[t] + EPS);
        wsf[608 + t] = i3;
        wsf[736 + t] = b3[t] - m3[t] * i3;
    }
}

// k1: x -> s1  (sign pack over 128 ch, 1x1 binconv via popcount, threshold)
__global__ __launch_bounds__(256) void k1_kernel(
    const float* __restrict__ x, const uint32_t* __restrict__ ws,
    uint32_t* __restrict__ s1)
{
    __shared__ uint32_t w1p[128];
    __shared__ float T1[32];
    int t = threadIdx.x;
    if (t < 128) w1p[t] = ws[t];
    if (t < 32)  T1[t] = ((const float*)ws)[544 + t];
    __syncthreads();

    int p   = blockIdx.x * 256 + t;
    int b   = p >> 15;          // / HW
    int rem = p & (HW - 1);
    const float* xb = x + (size_t)b * C * HW + rem;

    uint32_t m[4];
    #pragma unroll
    for (int wd = 0; wd < 4; ++wd) {
        uint32_t mm = 0;
        #pragma unroll
        for (int j = 0; j < 32; ++j) {
            float v = xb[(size_t)(wd * 32 + j) * HW];
            mm |= (v > 0.f ? 1u : 0u) << j;
        }
        m[wd] = mm;
    }

    uint32_t out = 0;
    #pragma unroll
    for (int ci = 0; ci < 32; ++ci) {
        int neq = __popc(m[0] ^ w1p[ci * 4 + 0]) + __popc(m[1] ^ w1p[ci * 4 + 1])
                + __popc(m[2] ^ w1p[ci * 4 + 2]) + __popc(m[3] ^ w1p[ci * 4 + 3]);
        float y1 = (float)(128 - 2 * neq);
        out |= (y1 > T1[ci] ? 1u : 0u) << ci;
    }
    s1[p] = out;
}

// k2: s1 -> s2  (3x3 binconv, zero-padding taps contribute 0)
__global__ __launch_bounds__(256) void k2_kernel(
    const uint32_t* __restrict__ s1, const uint32_t* __restrict__ ws,
    uint32_t* __restrict__ s2)
{
    __shared__ uint32_t w2p[288];
    __shared__ float T2[32];
    int t = threadIdx.x;
    for (int i = t; i < 288; i += 256) w2p[i] = ws[128 + i];
    if (t < 32) T2[t] = ((const float*)ws)[576 + t];
    __syncthreads();

    int p   = blockIdx.x * 256 + t;
    int b   = p >> 15;
    int rem = p & (HW - 1);
    int h   = rem >> 8;      // W = 256
    int w   = rem & 255;

    uint32_t n[9];
    uint32_t vmask = 0;
    int nv = 0;
    #pragma unroll
    for (int dy = -1; dy <= 1; ++dy) {
        #pragma unroll
        for (int dx = -1; dx <= 1; ++dx) {
            int tap = (dy + 1) * 3 + (dx + 1);
            int hh = h + dy, wv = w + dx;
            bool ok = (hh >= 0) & (hh < H) & (wv >= 0) & (wv < W);
            uint32_t val = 0;
            if (ok) val = s1[b * HW + hh * W + wv];
            n[tap] = val;
            vmask |= ok ? (1u << tap) : 0u;
            nv += ok ? 1 : 0;
        }
    }

    uint32_t out = 0;
    #pragma unroll
    for (int ci = 0; ci < 32; ++ci) {
        int neq = 0;
        #pragma unroll
        for (int tap = 0; tap < 9; ++tap) {
            int pc = __popc(n[tap] ^ w2p[ci * 9 + tap]);
            neq += ((vmask >> tap) & 1u) ? pc : 0;
        }
        float y2 = (float)(32 * nv - 2 * neq);
        out |= (y2 > T2[ci] ? 1u : 0u) << ci;
    }
    s2[p] = out;
}

// k3: s2 + x -> out  (1x1 expand popcount, BN3, PReLU, residual, PReLU)
__global__ __launch_bounds__(256) void k3_kernel(
    const float* __restrict__ x, const uint32_t* __restrict__ s2,
    const uint32_t* __restrict__ ws,
    const float* __restrict__ a3p, const float* __restrict__ aoutp,
    float* __restrict__ out)
{
    __shared__ uint32_t w3p[128];
    __shared__ float inv3[128], c3[128];
    int t = threadIdx.x;
    if (t < 128) {
        w3p[t]  = ws[416 + t];
        inv3[t] = ((const float*)ws)[608 + t];
        c3[t]   = ((const float*)ws)[736 + t];
    }
    __syncthreads();

    float a3 = a3p[0], aout = aoutp[0];
    int p   = blockIdx.x * 256 + t;
    int b   = p >> 15;
    int rem = p & (HW - 1);
    size_t base = (size_t)b * C * HW + rem;
    uint32_t sw = s2[p];

    #pragma unroll 8
    for (int c = 0; c < C; ++c) {
        int y3 = 32 - 2 * __popc(sw ^ w3p[c]);
        float hv = fmaf((float)y3, inv3[c], c3[c]);
        hv = hv < 0.f ? a3 * hv : hv;
        float o = hv + x[base + (size_t)c * HW];
        o = o < 0.f ? aout * o : o;
        out[base + (size_t)c * HW] = o;
    }
}

extern "C" void kernel_launch(void* const* d_in, const int* in_sizes, int n_in,
                              void* d_out, int out_size, void* d_ws, size_t ws_size,
                              hipStream_t stream)
{
    const float* x  = (const float*)d_in[0];
    const float* w1 = (const float*)d_in[1];
    const float* g1 = (const float*)d_in[2];
    const float* b1 = (const float*)d_in[3];
    const float* m1 = (const float*)d_in[4];
    const float* v1 = (const float*)d_in[5];
    // d_in[6] = a1 (scalar, sign-preserving, unused)
    const float* w2 = (const float*)d_in[7];
    const float* g2 = (const float*)d_in[8];
    const float* b2 = (const float*)d_in[9];
    const float* m2 = (const float*)d_in[10];
    const float* v2 = (const float*)d_in[11];
    // d_in[12] = a2 (unused)
    const float* w3 = (const float*)d_in[13];
    const float* g3 = (const float*)d_in[14];
    const float* b3 = (const float*)d_in[15];
    const float* m3 = (const float*)d_in[16];
    const float* v3 = (const float*)d_in[17];
    const float* a3 = (const float*)d_in[18];
    const float* ao = (const float*)d_in[19];

    uint32_t* ws = (uint32_t*)d_ws;
    uint32_t* s1 = ws + WS_S1;
    uint32_t* s2 = ws + WS_S2;
    float* out = (float*)d_out;

    hipLaunchKernelGGL(prep_kernel, dim3(1), dim3(256), 0, stream,
                       w1, g1, b1, m1, v1, w2, g2, b2, m2, v2, w3, g3, b3, m3, v3, ws);
    hipLaunchKernelGGL(k1_kernel, dim3(P / 256), dim3(256), 0, stream, x, ws, s1);
    hipLaunchKernelGGL(k2_kernel, dim3(P / 256), dim3(256), 0, stream, s1, ws, s2);
    hipLaunchKernelGGL(k3_kernel, dim3(P / 256), dim3(256), 0, stream, x, s2, ws, a3, ao, out);
}